// Round 1
// baseline (775.783 us; speedup 1.0000x reference)
//
#include <hip/hip_runtime.h>

// DesignerNetwork: B=1024 batch-independent graph-GRU network.
// Decomposition: 256 blocks x 256 threads; each block = 4 samples, 1 wave per
// sample. Wavefront form over nodes (adj is strictly upper triangular), all
// state + transposed weights in LDS, psi accumulated on the fly.

namespace {

constexpr int Bc = 1024;   // batch
constexpr int Nn = 32;     // nodes
constexpr int SP = 60;     // S_PHI == S_RHO
constexpr int NG = 180;    // 3*S_PHI gate rows
constexpr int BT = 4;      // batch tile per block (1 wave each)
constexpr int NA = 5;      // actions
constexpr int NR = 7;      // roles

// ---- LDS layout (float offsets) ----
constexpr int OFF_WX   = 0;                      // Wih^T staged [k*180 + r], 60x180
constexpr int OFF_WH   = OFF_WX + 60 * NG;       // Whh^T, 10800
constexpr int OFF_WP   = OFF_WH + 60 * NG;       // proj^T [k*60 + r], 80x60
constexpr int OFF_BX   = OFF_WP + 80 * SP;       // bih (pad 192)
constexpr int OFF_BH   = OFF_BX + 192;           // bhh (pad 192)
constexpr int OFF_BP   = OFF_BH + 192;           // bproj (pad 64)
constexpr int OFF_WU   = OFF_BP + 64;            // Wu 7x120
constexpr int OFF_BU   = OFF_WU + 840;           // bu (pad 8)
constexpr int OFF_WA   = OFF_BU + 8;             // Wa 5x120
constexpr int OFF_BA   = OFF_WA + 600;           // ba (pad 8)
constexpr int OFF_WC   = OFF_BA + 8;             // Wc 120
constexpr int OFF_BC   = OFF_WC + 120;           // bc (pad 8)
constexpr int OFF_HAS  = OFF_BC + 8;             // has[4][32]
constexpr int OFF_SLOT = OFF_HAS + 128;          // slots [4][32][60]: h then rho
constexpr int OFF_PSI  = OFF_SLOT + BT * Nn * SP;// psi acc [4][32][7]
constexpr int OFF_AH   = OFF_PSI + BT * Nn * NR; // alpha working h [4][64]
constexpr int OFF_AF   = OFF_AH + BT * 64;       // alpha_f [4][64]
constexpr int OFF_AB   = OFF_AF + BT * 64;       // alpha_b [4][64]
constexpr int OFF_OS   = OFF_AB + BT * 64;       // omega scratch [4][8]
constexpr int OFF_MASK = OFF_OS + BT * 8;        // uints: succ[32] pred[32] flags[4]
constexpr int LDS_FLOATS = OFF_MASK + 68 + 64;   // +64 pad for inactive-lane reads

__device__ __forceinline__ float sigm(float x) {
    return 1.0f / (1.0f + __expf(-x));
}

__device__ __forceinline__ float tanh_f(float x) {
    // tanh(x) = (e^{2x}-1)/(e^{2x}+1); clamp avoids inf/inf NaN, exact saturation anyway
    float e = __expf(fminf(2.0f * x, 80.0f));
    return (e - 1.0f) / (e + 1.0f);
}

// adj may arrive as int32 (0/1), packed uint8 bool, or float32. mode: 0/1/2.
__device__ __forceinline__ unsigned adj_nz(const unsigned* a, int mode, int r, int c) {
    const int idx = r * 32 + c;
    unsigned v = (mode == 1) ? ((a[idx >> 2] >> (8 * (idx & 3))) & 0xffu) : a[idx];
    return v != 0u ? 1u : 0u;
}

__device__ void stage_dir(float* lds, const float* Wih, const float* Whh,
                          const float* bih, const float* bhh,
                          const float* Wp, const float* bp, int tid) {
    for (int i = tid; i < 10800; i += 256) {        // coalesced global read, transpose to LDS
        const int r = i / 60, k = i - r * 60;
        lds[OFF_WX + k * NG + r] = Wih[i];
        lds[OFF_WH + k * NG + r] = Whh[i];
    }
    for (int i = tid; i < 4800; i += 256) {         // proj (60,80) -> WP[k*60+r]
        const int r = i / 80, k = i - r * 80;
        lds[OFF_WP + k * SP + r] = Wp[i];
    }
    if (tid < NG) { lds[OFF_BX + tid] = bih[tid]; lds[OFF_BH + tid] = bhh[tid]; }
    if (tid < SP) lds[OFF_BP + tid] = bp[tid];
    for (int i = tid; i < BT * Nn * SP; i += 256) lds[OFF_SLOT + i] = 0.0f;  // zero h states
}

// Full GRU step (x-matvec + h-matvec) for the alpha scans.
__device__ __forceinline__ float gru_step(const float* lds, const float* x,
                                          const float* hvec, int lane) {
    const float* WX = lds + OFF_WX;
    const float* WH = lds + OFF_WH;
    float g0 = lds[OFF_BX + lane], g1 = lds[OFF_BX + 60 + lane], g2 = lds[OFF_BX + 120 + lane];
    float a0 = lds[OFF_BH + lane], a1 = lds[OFF_BH + 60 + lane], a2 = lds[OFF_BH + 120 + lane];
#pragma unroll
    for (int k = 0; k < SP; ++k) {
        const float xk = x[k];
        const float hk = hvec[k];
        g0 = fmaf(WX[k * NG + lane], xk, g0);
        g1 = fmaf(WX[k * NG + 60 + lane], xk, g1);
        g2 = fmaf(WX[k * NG + 120 + lane], xk, g2);
        a0 = fmaf(WH[k * NG + lane], hk, a0);
        a1 = fmaf(WH[k * NG + 60 + lane], hk, a1);
        a2 = fmaf(WH[k * NG + 120 + lane], hk, a2);
    }
    const float r = sigm(g0 + a0);
    const float u = sigm(g1 + a1);
    const float n = tanh_f(fmaf(r, a2, g2));
    const float h = hvec[lane];
    return fmaf(u, h - n, n);   // (1-u)*n + u*h
}

template <int FWD>
__device__ void run_phase(float* lds, const float* zg, const float* dzg,
                          int b, int w, int lane) {
    float* slot = lds + OFF_SLOT + w * (Nn * SP);
    const float* WX = lds + OFF_WX;
    const float* WH = lds + OFF_WH;
    const float* WP = lds + OFF_WP;
    const unsigned* succm = (const unsigned*)(lds + OFF_MASK);
    const unsigned* predm = succm + 32;
    const bool act = lane < SP;

    for (int s = 0; s < Nn; ++s) {
        const int t = FWD ? s : (Nn - 1 - s);
        const float* hv = slot + t * SP;

        // ---- finalize rho[t] = proj([h, z_t, dz_t]) (tanh only in fwd) ----
        float acc = lds[OFF_BP + lane];
#pragma unroll
        for (int k = 0; k < SP; ++k) acc = fmaf(WP[k * SP + lane], hv[k], acc);
        {
            const float* zp = zg + (b * Nn + t) * 10;
            const float* dp = dzg + (b * Nn + t) * 10;
#pragma unroll
            for (int k = 0; k < 10; ++k) acc = fmaf(WP[(60 + k) * SP + lane], zp[k], acc);
#pragma unroll
            for (int k = 0; k < 10; ++k) acc = fmaf(WP[(70 + k) * SP + lane], dp[k], acc);
        }
        if (FWD) acc = tanh_f(acc);
        __builtin_amdgcn_wave_barrier();
        if (act) slot[t * SP + lane] = acc;       // slot t now holds rho[t]
        __builtin_amdgcn_wave_barrier();

        // ---- psi (role-logit) contribution of this node ----
        if (lane < NR) {
            const float* wu = lds + OFF_WU + lane * 120 + (FWD ? 0 : 60);
            float p = 0.0f;
#pragma unroll
            for (int k = 0; k < SP; ++k) p = fmaf(wu[k], hv[k], p);
            float* pp = lds + OFF_PSI + (w * Nn + t) * NR + lane;
            *pp = FWD ? p : (*pp + p);
        }

        // ---- GRU push to successors (select gated by has[b,t], wave-uniform) ----
        const float hb = lds[OFF_HAS + w * 32 + t];
        unsigned m = FWD ? succm[t] : predm[t];
        if (hb != 0.0f && m != 0u) {
            // gi = Wih^T rho[t] + bih, hoisted across all successors
            float g0 = lds[OFF_BX + lane];
            float g1 = lds[OFF_BX + 60 + lane];
            float g2 = lds[OFF_BX + 120 + lane];
#pragma unroll
            for (int k = 0; k < SP; ++k) {
                const float xk = hv[k];
                g0 = fmaf(WX[k * NG + lane], xk, g0);
                g1 = fmaf(WX[k * NG + 60 + lane], xk, g1);
                g2 = fmaf(WX[k * NG + 120 + lane], xk, g2);
            }
            while (m) {
                const int i = __ffs(m) - 1;
                m &= m - 1u;
                float* hs = slot + i * SP;
                float a0 = lds[OFF_BH + lane];
                float a1 = lds[OFF_BH + 60 + lane];
                float a2 = lds[OFF_BH + 120 + lane];
#pragma unroll
                for (int k = 0; k < SP; ++k) {
                    const float hk = hs[k];
                    a0 = fmaf(WH[k * NG + lane], hk, a0);
                    a1 = fmaf(WH[k * NG + 60 + lane], hk, a1);
                    a2 = fmaf(WH[k * NG + 120 + lane], hk, a2);
                }
                const float r = sigm(g0 + a0);
                const float u = sigm(g1 + a1);
                const float n = tanh_f(fmaf(r, a2, g2));
                const float hold = hs[lane];
                const float hnew = fmaf(u, hold - n, n);
                __builtin_amdgcn_wave_barrier();
                if (act) hs[lane] = hnew;
                __builtin_amdgcn_wave_barrier();
            }
        }
    }
}

template <int FWD>
__device__ void run_alpha(float* lds, int w, int lane) {
    float* slot = lds + OFF_SLOT + w * (Nn * SP);
    float* ah = lds + OFF_AH + w * 64;
    const bool act = lane < SP;
    if (act) ah[lane] = 0.0f;
    __builtin_amdgcn_wave_barrier();
    const int cnt = FWD ? 5 : 6;    // O_OUT=5 fwd nodes 27..31 ; I_IN=6 bwd nodes 5..0
    for (int s = 0; s < cnt; ++s) {
        const int i = FWD ? (Nn - 5 + s) : (5 - s);
        const float hbv = lds[OFF_HAS + w * 32 + i];
        if (hbv == 0.0f) continue;          // select keeps old h
        const float hnew = gru_step(lds, slot + i * SP, ah, lane);
        __builtin_amdgcn_wave_barrier();
        if (act) ah[lane] = hnew;
        __builtin_amdgcn_wave_barrier();
    }
    float* dst = lds + (FWD ? OFF_AF : OFF_AB) + w * 64;
    if (act) dst[lane] = ah[lane];
    __builtin_amdgcn_wave_barrier();
}

__device__ void run_heads(float* lds, int b, int w, int lane, float* out) {
    const float* aF = lds + OFF_AF + w * 64;
    const float* aB = lds + OFF_AB + w * 64;

    // omega rows on lanes 0..4, value on lane 5
    float o = 0.0f;
    if (lane < NA) {
        o = lds[OFF_BA + lane];
        const float* wa = lds + OFF_WA + lane * 120;
#pragma unroll
        for (int k = 0; k < SP; ++k) o = fmaf(wa[k], aF[k], o);
#pragma unroll
        for (int k = 0; k < SP; ++k) o = fmaf(wa[60 + k], aB[k], o);
        lds[OFF_OS + w * 8 + lane] = o;
    } else if (lane == NA) {
        float v = lds[OFF_BC];
        const float* wc = lds + OFF_WC;
#pragma unroll
        for (int k = 0; k < SP; ++k) v = fmaf(wc[k], aF[k], v);
#pragma unroll
        for (int k = 0; k < SP; ++k) v = fmaf(wc[60 + k], aB[k], v);
        out[Bc * NA + Bc * NR * Nn + b] = v;
    }
    __builtin_amdgcn_wave_barrier();

    // instr softmax (5)
    if (lane < NA) {
        const float* os = lds + OFF_OS + w * 8;
        float mx = os[0];
#pragma unroll
        for (int j = 1; j < NA; ++j) mx = fmaxf(mx, os[j]);
        float sum = 0.0f;
#pragma unroll
        for (int j = 0; j < NA; ++j) sum += __expf(os[j] - mx);
        out[b * NA + lane] = __expf(o - mx) / sum;
    }

    // role softmax: lane = node i, loop over 7 roles
    if (lane < Nn) {
        const int i = lane;
        const float mk = lds[OFF_HAS + w * 32 + i];
        float p[NR];
        float mx = -1e30f;
#pragma unroll
        for (int c = 0; c < NR; ++c) {
            const float v = (mk != 0.0f)
                ? (lds[OFF_PSI + (w * Nn + i) * NR + c] + lds[OFF_BU + c])
                : -60.0f;
            p[c] = v;
            mx = fmaxf(mx, v);
        }
        float sum = 0.0f;
#pragma unroll
        for (int c = 0; c < NR; ++c) { p[c] = __expf(p[c] - mx); sum += p[c]; }
        const float inv = 1.0f / sum;
#pragma unroll
        for (int c = 0; c < NR; ++c)
            out[Bc * NA + b * (NR * Nn) + c * Nn + i] = p[c] * inv;
    }
}

__global__ __launch_bounds__(256, 1)
void dn_kernel(const float* __restrict__ has, const float* __restrict__ z,
               const float* __restrict__ dz, const unsigned* __restrict__ adjw,
               const float* __restrict__ Wih_f, const float* __restrict__ Whh_f,
               const float* __restrict__ bih_f, const float* __restrict__ bhh_f,
               const float* __restrict__ Wih_b, const float* __restrict__ Whh_b,
               const float* __restrict__ bih_b, const float* __restrict__ bhh_b,
               const float* __restrict__ Wf, const float* __restrict__ bf,
               const float* __restrict__ Wb, const float* __restrict__ bb,
               const float* __restrict__ Wa, const float* __restrict__ ba,
               const float* __restrict__ Wc, const float* __restrict__ bc,
               const float* __restrict__ Wu, const float* __restrict__ bu,
               float* __restrict__ out) {
    extern __shared__ float lds[];
    const int tid = threadIdx.x;
    const int lane = tid & 63;
    const int w = tid >> 6;
    const int b = blockIdx.x * BT + w;

    unsigned* succm = (unsigned*)(lds + OFF_MASK);
    unsigned* predm = succm + 32;
    unsigned* flags = predm + 32;

    if (tid < 4) flags[tid] = 0u;
    __syncthreads();

    // ---- adj dtype detection: only first 256 words (safe for all encodings) ----
    {
        unsigned ff = 0u, fb = 0u;
        for (int i = tid; i < 256; i += 256) {
            const unsigned v = adjw[i];
            ff |= (v == 0x3f800000u) ? 1u : 0u;
            fb |= (v > 1u && v != 0x3f800000u) ? 1u : 0u;
        }
        if (ff) atomicOr(&flags[0], 1u);
        if (fb) atomicOr(&flags[1], 1u);
    }
    // ---- stage head weights + has (independent of flags) ----
    for (int i = tid; i < 840; i += 256) lds[OFF_WU + i] = Wu[i];
    for (int i = tid; i < 600; i += 256) lds[OFF_WA + i] = Wa[i];
    if (tid < 120) lds[OFF_WC + tid] = Wc[tid];
    if (tid < NR) lds[OFF_BU + tid] = bu[tid];
    if (tid < NA) lds[OFF_BA + tid] = ba[tid];
    if (tid == 0) lds[OFF_BC] = bc[0];
    if (lane < Nn) lds[OFF_HAS + w * 32 + lane] = has[b * 32 + lane];
    __syncthreads();

    // ---- adjacency bitmasks (rows = successors, cols = bwd receivers) ----
    const int mode = flags[0] ? 2 : (flags[1] ? 1 : 0);
    if (tid < 32) {
        unsigned sm = 0u;
        for (int c = 0; c < 32; ++c) sm |= adj_nz(adjw, mode, tid, c) << c;
        succm[tid] = sm;
    } else if (tid < 64) {
        const int c = tid - 32;
        unsigned pm = 0u;
        for (int r = 0; r < 32; ++r) pm |= adj_nz(adjw, mode, r, c) << r;
        predm[c] = pm;
    }
    stage_dir(lds, Wih_f, Whh_f, bih_f, bhh_f, Wf, bf, tid);
    __syncthreads();

    run_phase<1>(lds, z, dz, b, w, lane);
    run_alpha<1>(lds, w, lane);
    __syncthreads();

    stage_dir(lds, Wih_b, Whh_b, bih_b, bhh_b, Wb, bb, tid);
    __syncthreads();

    run_phase<0>(lds, z, dz, b, w, lane);
    run_alpha<0>(lds, w, lane);

    run_heads(lds, b, w, lane, out);
}

}  // namespace

extern "C" void kernel_launch(void* const* d_in, const int* in_sizes, int n_in,
                              void* d_out, int out_size, void* d_ws, size_t ws_size,
                              hipStream_t stream) {
    (void)in_sizes; (void)n_in; (void)out_size; (void)d_ws; (void)ws_size;
    const float* has     = (const float*)d_in[0];
    const float* z       = (const float*)d_in[1];
    const float* dz      = (const float*)d_in[2];
    const unsigned* adjw = (const unsigned*)d_in[3];
    const float* Wih_f   = (const float*)d_in[4];
    const float* Whh_f   = (const float*)d_in[5];
    const float* bih_f   = (const float*)d_in[6];
    const float* bhh_f   = (const float*)d_in[7];
    const float* Wih_b   = (const float*)d_in[8];
    const float* Whh_b   = (const float*)d_in[9];
    const float* bih_b   = (const float*)d_in[10];
    const float* bhh_b   = (const float*)d_in[11];
    const float* Wf      = (const float*)d_in[12];
    const float* bf      = (const float*)d_in[13];
    const float* Wb      = (const float*)d_in[14];
    const float* bb      = (const float*)d_in[15];
    const float* Wa      = (const float*)d_in[16];
    const float* ba      = (const float*)d_in[17];
    const float* Wc      = (const float*)d_in[18];
    const float* bc      = (const float*)d_in[19];
    const float* Wu      = (const float*)d_in[20];
    const float* bu      = (const float*)d_in[21];
    float* out = (float*)d_out;

    const size_t ldsBytes = (size_t)LDS_FLOATS * sizeof(float);
    hipFuncSetAttribute(reinterpret_cast<const void*>(dn_kernel),
                        hipFuncAttributeMaxDynamicSharedMemorySize, (int)ldsBytes);
    dn_kernel<<<Bc / BT, 256, ldsBytes, stream>>>(
        has, z, dz, adjw, Wih_f, Whh_f, bih_f, bhh_f,
        Wih_b, Whh_b, bih_b, bhh_b, Wf, bf, Wb, bb,
        Wa, ba, Wc, bc, Wu, bu, out);
}

// Round 3
// 467.519 us; speedup vs baseline: 1.6594x; 1.6594x over previous
//
#include <hip/hip_runtime.h>

// DesignerNetwork: B=1024 batch-independent graph-GRU network.
// Round 2 (resubmit after broker timeout): 1 block = 1 sample, 4 waves
// cooperatively k-split every matvec (15 of 60 k per wave). Weights in VGPRs,
// node states replicated in LDS, one __syncthreads per GRU step
// (double-buffered float4 partial exchange).

namespace {

constexpr int Bc = 1024;   // batch
constexpr int Nn = 32;     // nodes
constexpr int SP = 60;     // S_PHI == S_RHO
constexpr int NA = 5;      // actions
constexpr int NR = 7;      // roles
constexpr int KW = 15;     // GRU k per wave (60/4)
constexpr int PW = 20;     // proj k per wave (80/4)

// ---- LDS layout (float offsets) ----
constexpr int OFF_STF  = 0;                     // rho_f/h_f states [32][64]
constexpr int OFF_STB  = OFF_STF + Nn * 64;     // rho_b/h_b states [32][64]
constexpr int OFF_PART = OFF_STB + Nn * 64;     // partials [2][4][64][4] floats
constexpr int OFF_ZDZ  = OFF_PART + 2048;       // z/dz staged [32][20]
constexpr int OFF_PSI  = OFF_ZDZ + Nn * PW;     // psi raw [32][8]
constexpr int OFF_WU   = OFF_PSI + Nn * 8;      // Wu 7x120
constexpr int OFF_WA   = OFF_WU + 840;          // Wa 5x120
constexpr int OFF_WC   = OFF_WA + 600;          // Wc 120
constexpr int OFF_BA   = OFF_WC + 120;          // ba (pad 8)
constexpr int OFF_BU   = OFF_BA + 8;            // bu (pad 8)
constexpr int OFF_BC   = OFF_BU + 8;            // bc (pad 4)
constexpr int OFF_HAS  = OFF_BC + 4;            // has[32]
constexpr int OFF_AF   = OFF_HAS + 32;          // alpha_f [64] (also working h)
constexpr int OFF_AB   = OFF_AF + 64;           // alpha_b [64]
constexpr int OFF_OS   = OFF_AB + 64;           // omega scratch [8]
constexpr int OFF_MASK = OFF_OS + 8;            // uints: succ[32] pred[32] flags[4]
constexpr int LDS_FLOATS = OFF_MASK + 68 + 8;

__device__ __forceinline__ float sigm(float x) {
    return 1.0f / (1.0f + __expf(-x));
}

__device__ __forceinline__ float tanh_f(float x) {
    float e = __expf(fminf(2.0f * x, 80.0f));
    return (e - 1.0f) / (e + 1.0f);
}

// adj may arrive as int32 (0/1), packed uint8 bool, or float32. mode: 0/1/2.
__device__ __forceinline__ unsigned adj_nz(const unsigned* a, int mode, int r, int c) {
    const int idx = r * 32 + c;
    unsigned v = (mode == 1) ? ((a[idx >> 2] >> (8 * (idx & 3))) & 0xffu) : a[idx];
    return v != 0u ? 1u : 0u;
}

__device__ __forceinline__ float4 ldq(const float* lds, int par, int ww, int lane) {
    return *(const float4*)(lds + OFF_PART + ((par * 4 + ww) * 64 + lane) * 4);
}

// One cooperative GRU update of LDS h-vector hv (row stride 64).
// gi partials (x-side) precomputed by caller.
// hold (old h) is read PRE-barrier; all waves write identical hnew.
__device__ __forceinline__ void gru_coop(float* lds, float* hv,
        const float (&wh)[3][KW], float gi0, float gi1, float gi2,
        float b0s, float b1s, float b2i, float b2h,
        int w, int lane, int& par) {
    float g0 = 0.f, g1 = 0.f, g2 = 0.f;
    const float* hk = hv + KW * w;
#pragma unroll
    for (int kk = 0; kk < KW; ++kk) {
        const float h = hk[kk];
        g0 = fmaf(wh[0][kk], h, g0);
        g1 = fmaf(wh[1][kk], h, g1);
        g2 = fmaf(wh[2][kk], h, g2);
    }
    const float hold = hv[lane];          // pre-barrier read of old state
    float4 q;
    q.x = gi0 + g0; q.y = gi1 + g1; q.z = gi2; q.w = g2;
    *(float4*)(lds + OFF_PART + ((par * 4 + w) * 64 + lane) * 4) = q;
    __syncthreads();
    const float4 q0 = ldq(lds, par, 0, lane);
    const float4 q1 = ldq(lds, par, 1, lane);
    const float4 q2 = ldq(lds, par, 2, lane);
    const float4 q3 = ldq(lds, par, 3, lane);
    par ^= 1;
    const float a0  = q0.x + q1.x + q2.x + q3.x + b0s;
    const float a1  = q0.y + q1.y + q2.y + q3.y + b1s;
    const float a2i = q0.z + q1.z + q2.z + q3.z + b2i;
    const float a2h = q0.w + q1.w + q2.w + q3.w + b2h;
    const float r = sigm(a0);
    const float u = sigm(a1);
    const float n = tanh_f(fmaf(r, a2h, a2i));
    const float hnew = fmaf(u, hold - n, n);
    if (lane < SP) hv[lane] = hnew;       // every wave writes identical value
}

__device__ __forceinline__ void load_weights(const float* __restrict__ Wih,
        const float* __restrict__ Whh, const float* __restrict__ bih,
        const float* __restrict__ bhh, const float* __restrict__ Wp,
        const float* __restrict__ bp, int w, int ln,
        float (&wh)[3][KW], float (&wx)[3][KW], float (&wp)[PW],
        float& b0s, float& b1s, float& b2i, float& b2h, float& bpv) {
#pragma unroll
    for (int g = 0; g < 3; ++g) {
        const float* hrow = Whh + (g * 60 + ln) * 60 + KW * w;
        const float* xrow = Wih + (g * 60 + ln) * 60 + KW * w;
#pragma unroll
        for (int kk = 0; kk < KW; ++kk) { wh[g][kk] = hrow[kk]; wx[g][kk] = xrow[kk]; }
    }
    const int pk = (w < 3) ? PW * w : 60;     // waves 0-2: h part, wave 3: z/dz part
    const float* prow = Wp + ln * 80 + pk;
#pragma unroll
    for (int kk = 0; kk < PW; ++kk) wp[kk] = prow[kk];
    b0s = bih[ln] + bhh[ln];
    b1s = bih[60 + ln] + bhh[60 + ln];
    b2i = bih[120 + ln];
    b2h = bhh[120 + ln];
    bpv = bp[ln];
}

template <int FWD>
__device__ __forceinline__ void run_dir(float* lds,
        const float (&wh)[3][KW], const float (&wx)[3][KW], const float (&wp)[PW],
        float b0s, float b1s, float b2i, float b2h, float bpv,
        int w, int lane, int& par) {
    float* st = lds + (FWD ? OFF_STF : OFF_STB);
    const unsigned* succm = (const unsigned*)(lds + OFF_MASK);
    const unsigned* predm = succm + 32;

    for (int s = 0; s < Nn; ++s) {
        const int t = FWD ? s : (Nn - 1 - s);

        // ---- finalize rho[t]: cooperative proj over [h(60); z(10); dz(10)] ----
        float pp = 0.f;
        const float* xb = (w < 3) ? (st + t * 64 + PW * w) : (lds + OFF_ZDZ + t * PW);
#pragma unroll
        for (int kk = 0; kk < PW; ++kk) pp = fmaf(wp[kk], xb[kk], pp);
        lds[OFF_PART + ((par * 4 + w) * 64 + lane) * 4] = pp;
        __syncthreads();
        float sum = lds[OFF_PART + ((par * 4 + 0) * 64 + lane) * 4]
                  + lds[OFF_PART + ((par * 4 + 1) * 64 + lane) * 4]
                  + lds[OFF_PART + ((par * 4 + 2) * 64 + lane) * 4]
                  + lds[OFF_PART + ((par * 4 + 3) * 64 + lane) * 4] + bpv;
        par ^= 1;
        const float rho = FWD ? tanh_f(sum) : sum;
        if (lane < SP) st[t * 64 + lane] = rho;   // replicated identical write

        // ---- GRU pushes to graph neighbors, gated by has[t] (block-uniform) ----
        const float hb = lds[OFF_HAS + t];
        unsigned m = FWD ? succm[t] : predm[t];
        if (hb != 0.f && m != 0u) {
            float gi0 = 0.f, gi1 = 0.f, gi2 = 0.f;   // x-side hoisted per node
            const float* xv = st + t * 64 + KW * w;
#pragma unroll
            for (int kk = 0; kk < KW; ++kk) {
                const float xk = xv[kk];
                gi0 = fmaf(wx[0][kk], xk, gi0);
                gi1 = fmaf(wx[1][kk], xk, gi1);
                gi2 = fmaf(wx[2][kk], xk, gi2);
            }
            while (m) {
                const int i = __ffs(m) - 1;
                m &= m - 1u;
                gru_coop(lds, st + i * 64, wh, gi0, gi1, gi2,
                         b0s, b1s, b2i, b2h, w, lane, par);
            }
        }
    }

    // ---- alpha scan (uses this direction's weights + rho in st) ----
    float* ah = lds + (FWD ? OFF_AF : OFF_AB);
    ah[lane] = 0.f;                               // replicated identical write
    const int cnt = FWD ? 5 : 6;
    for (int s2 = 0; s2 < cnt; ++s2) {
        const int i = FWD ? (Nn - 5 + s2) : (5 - s2);
        if (lds[OFF_HAS + i] == 0.f) continue;    // block-uniform skip
        float gi0 = 0.f, gi1 = 0.f, gi2 = 0.f;
        const float* xv = st + i * 64 + KW * w;
#pragma unroll
        for (int kk = 0; kk < KW; ++kk) {
            const float xk = xv[kk];
            gi0 = fmaf(wx[0][kk], xk, gi0);
            gi1 = fmaf(wx[1][kk], xk, gi1);
            gi2 = fmaf(wx[2][kk], xk, gi2);
        }
        gru_coop(lds, ah, wh, gi0, gi1, gi2, b0s, b1s, b2i, b2h, w, lane, par);
    }
}

__device__ void run_heads(float* lds, int b, int lane, float* __restrict__ out) {
    const float* aF = lds + OFF_AF;
    const float* aB = lds + OFF_AB;

    float o = 0.f;
    if (lane < NA) {
        o = lds[OFF_BA + lane];
        const float* wa = lds + OFF_WA + lane * 120;
#pragma unroll
        for (int k = 0; k < SP; ++k) o = fmaf(wa[k], aF[k], o);
#pragma unroll
        for (int k = 0; k < SP; ++k) o = fmaf(wa[60 + k], aB[k], o);
        lds[OFF_OS + lane] = o;
    } else if (lane == NA) {
        float v = lds[OFF_BC];
        const float* wc = lds + OFF_WC;
#pragma unroll
        for (int k = 0; k < SP; ++k) v = fmaf(wc[k], aF[k], v);
#pragma unroll
        for (int k = 0; k < SP; ++k) v = fmaf(wc[60 + k], aB[k], v);
        out[Bc * NA + Bc * NR * Nn + b] = v;
    }
    __builtin_amdgcn_wave_barrier();

    if (lane < NA) {
        const float* os = lds + OFF_OS;
        float mx = os[0];
#pragma unroll
        for (int j = 1; j < NA; ++j) mx = fmaxf(mx, os[j]);
        float sum = 0.f;
#pragma unroll
        for (int j = 0; j < NA; ++j) sum += __expf(os[j] - mx);
        out[b * NA + lane] = __expf(o - mx) / sum;
    }

    if (lane < Nn) {
        const int i = lane;
        const float mk = lds[OFF_HAS + i];
        float p[NR];
        float mx = -1e30f;
#pragma unroll
        for (int c = 0; c < NR; ++c) {
            const float v = (mk != 0.f)
                ? (lds[OFF_PSI + i * 8 + c] + lds[OFF_BU + c])
                : -60.0f;
            p[c] = v;
            mx = fmaxf(mx, v);
        }
        float sum = 0.f;
#pragma unroll
        for (int c = 0; c < NR; ++c) { p[c] = __expf(p[c] - mx); sum += p[c]; }
        const float inv = 1.0f / sum;
#pragma unroll
        for (int c = 0; c < NR; ++c)
            out[Bc * NA + b * (NR * Nn) + c * Nn + i] = p[c] * inv;
    }
}

__global__ __launch_bounds__(256, 3)
void dn_kernel(const float* __restrict__ has, const float* __restrict__ z,
               const float* __restrict__ dz, const unsigned* __restrict__ adjw,
               const float* __restrict__ Wih_f, const float* __restrict__ Whh_f,
               const float* __restrict__ bih_f, const float* __restrict__ bhh_f,
               const float* __restrict__ Wih_b, const float* __restrict__ Whh_b,
               const float* __restrict__ bih_b, const float* __restrict__ bhh_b,
               const float* __restrict__ Wf, const float* __restrict__ bf,
               const float* __restrict__ Wb, const float* __restrict__ bb,
               const float* __restrict__ Wa, const float* __restrict__ ba,
               const float* __restrict__ Wc, const float* __restrict__ bc,
               const float* __restrict__ Wu, const float* __restrict__ bu,
               float* __restrict__ out) {
    __shared__ float lds[LDS_FLOATS];
    const int tid = threadIdx.x;
    const int lane = tid & 63;
    const int w = tid >> 6;
    const int b = blockIdx.x;
    const int ln = (lane < SP) ? lane : (SP - 1);   // clamp for weight/bias loads

    unsigned* succm = (unsigned*)(lds + OFF_MASK);
    unsigned* predm = succm + 32;
    unsigned* flags = predm + 32;

    if (tid < 4) flags[tid] = 0u;
    __syncthreads();

    // ---- adj dtype detection (first 256 words only) ----
    {
        unsigned ff = 0u, fb = 0u;
        for (int i = tid; i < 256; i += 256) {
            const unsigned v = adjw[i];
            ff |= (v == 0x3f800000u) ? 1u : 0u;
            fb |= (v > 1u && v != 0x3f800000u) ? 1u : 0u;
        }
        if (ff) atomicOr(&flags[0], 1u);
        if (fb) atomicOr(&flags[1], 1u);
    }

    // ---- stage head weights, has, z/dz; zero both state arrays ----
    for (int i = tid; i < 840; i += 256) lds[OFF_WU + i] = Wu[i];
    for (int i = tid; i < 600; i += 256) lds[OFF_WA + i] = Wa[i];
    if (tid < 120) lds[OFF_WC + tid] = Wc[tid];
    if (tid < NR) lds[OFF_BU + tid] = bu[tid];
    if (tid < NA) lds[OFF_BA + tid] = ba[tid];
    if (tid == 0) lds[OFF_BC] = bc[0];
    if (tid < Nn) lds[OFF_HAS + tid] = has[b * 32 + tid];
    for (int i = tid; i < Nn * PW; i += 256) {
        const int t = i / PW, k = i - t * PW;
        lds[OFF_ZDZ + i] = (k < 10) ? z[(b * Nn + t) * 10 + k]
                                    : dz[(b * Nn + t) * 10 + (k - 10)];
    }
    for (int i = tid; i < 2 * Nn * 64; i += 256) lds[OFF_STF + i] = 0.f;
    __syncthreads();

    // ---- adjacency bitmasks ----
    const int mode = flags[0] ? 2 : (flags[1] ? 1 : 0);
    if (tid < 32) {
        unsigned sm = 0u;
        for (int c = 0; c < 32; ++c) sm |= adj_nz(adjw, mode, tid, c) << c;
        succm[tid] = sm;
    } else if (tid < 64) {
        const int c = tid - 32;
        unsigned pm = 0u;
        for (int r = 0; r < 32; ++r) pm |= adj_nz(adjw, mode, r, c) << r;
        predm[c] = pm;
    }
    __syncthreads();

    int par = 0;
    float wh[3][KW], wx[3][KW], wp[PW];
    float b0s, b1s, b2i, b2h, bpv;

    load_weights(Wih_f, Whh_f, bih_f, bhh_f, Wf, bf, w, ln,
                 wh, wx, wp, b0s, b1s, b2i, b2h, bpv);
    run_dir<1>(lds, wh, wx, wp, b0s, b1s, b2i, b2h, bpv, w, lane, par);

    load_weights(Wih_b, Whh_b, bih_b, bhh_b, Wb, bb, w, ln,
                 wh, wx, wp, b0s, b1s, b2i, b2h, bpv);
    run_dir<0>(lds, wh, wx, wp, b0s, b1s, b2i, b2h, bpv, w, lane, par);
    __syncthreads();

    // ---- psi: 224 threads, one (node, role) dot each ----
    if (tid < Nn * NR) {
        const int i = tid / NR, c = tid - i * NR;
        const float* wu = lds + OFF_WU + c * 120;
        const float* sf = lds + OFF_STF + i * 64;
        const float* sb = lds + OFF_STB + i * 64;
        float acc = 0.f;
#pragma unroll
        for (int k = 0; k < SP; ++k)
            acc = fmaf(wu[k], sf[k], fmaf(wu[60 + k], sb[k], acc));
        lds[OFF_PSI + i * 8 + c] = acc;
    }
    __syncthreads();

    if (w == 0) run_heads(lds, b, lane, out);
}

}  // namespace

extern "C" void kernel_launch(void* const* d_in, const int* in_sizes, int n_in,
                              void* d_out, int out_size, void* d_ws, size_t ws_size,
                              hipStream_t stream) {
    (void)in_sizes; (void)n_in; (void)out_size; (void)d_ws; (void)ws_size;
    const float* has     = (const float*)d_in[0];
    const float* z       = (const float*)d_in[1];
    const float* dz      = (const float*)d_in[2];
    const unsigned* adjw = (const unsigned*)d_in[3];
    const float* Wih_f   = (const float*)d_in[4];
    const float* Whh_f   = (const float*)d_in[5];
    const float* bih_f   = (const float*)d_in[6];
    const float* bhh_f   = (const float*)d_in[7];
    const float* Wih_b   = (const float*)d_in[8];
    const float* Whh_b   = (const float*)d_in[9];
    const float* bih_b   = (const float*)d_in[10];
    const float* bhh_b   = (const float*)d_in[11];
    const float* Wf      = (const float*)d_in[12];
    const float* bf      = (const float*)d_in[13];
    const float* Wb      = (const float*)d_in[14];
    const float* bb      = (const float*)d_in[15];
    const float* Wa      = (const float*)d_in[16];
    const float* ba      = (const float*)d_in[17];
    const float* Wc      = (const float*)d_in[18];
    const float* bc      = (const float*)d_in[19];
    const float* Wu      = (const float*)d_in[20];
    const float* bu      = (const float*)d_in[21];
    float* out = (float*)d_out;

    dn_kernel<<<Bc, 256, 0, stream>>>(
        has, z, dz, adjw, Wih_f, Whh_f, bih_f, bhh_f,
        Wih_b, Whh_b, bih_b, bhh_b, Wf, bf, Wb, bb,
        Wa, ba, Wc, bc, Wu, bu, out);
}